// Round 1
// baseline (619.673 us; speedup 1.0000x reference)
//
#include <hip/hip_runtime.h>
#include <math.h>

// ExpertGating: g = x @ gate_w^T + gate_b (16384x4096 @ 4096x64), top-8 desc
// (tie -> lowest idx), softmax. out: [0,131072) weights, [131072,262144) idx-as-float.
//
// R4 redesign: barrier-free direct-to-register MFMA streaming.
//  - A-fragment (token rows) loaded straight from global fp32, split to bf16
//    hi/lo in-register (v_perm packing, 3 VALU/float). No LDS staging.
//  - B (gate_w) pre-split ONCE into bf16 hi/lo planes in workspace by a tiny
//    pre-kernel; main kernel loads B fragments directly (16 B/lane).
//  - 1024 blocks x 256 thr: wave = 16 tokens x 16 experts -> 4 blocks/CU,
//    4 waves/SIMD, no __syncthreads in the K-loop (raw s_barrier every 16
//    chunks only to bound wave drift so shared A lines stay cached; raw
//    barrier has no vmcnt drain -> prefetch spans it).
//  - Numerics identical to R3: truncation split, 4 MFMA passes (hh+hl+lh+ll),
//    fp32 acc, MARGIN=2.5e-4 + fp64 recompute fallback for close calls.
//  - Epilogue: wave-parallel top-9 (16 lanes/token, shfl_xor butterfly)
//    replaces the 576-iteration serial scan.

#define NT 16384
#define HID 4096
#define NE 64
#define TOPK 8
#define BT 16          // tokens per block (one 16-row MFMA tile)
#define LG_S 65
#define MARGIN 2.5e-4f

typedef __attribute__((ext_vector_type(8))) short bf16x8;
typedef __attribute__((ext_vector_type(4))) float f32x4;

union BF8 { unsigned int u[4]; bf16x8 v; };

// pack two fp32 -> one dword holding [bf16(b):bf16(a)] (truncation split, hi part)
__device__ __forceinline__ unsigned int hi_pack(float a, float b) {
    // result byte0,1 = a bytes 2,3 (sel 2,3); byte2,3 = b bytes 2,3 (sel 6,7)
    return __builtin_amdgcn_perm(__float_as_uint(b), __float_as_uint(a), 0x07060302u);
}

__device__ __forceinline__ float lo_of(float f) {
    return f - __uint_as_float(__float_as_uint(f) & 0xFFFF0000u);
}

__device__ __forceinline__ bf16x8 pack_hi8(float4 a, float4 b) {
    BF8 r;
    r.u[0] = hi_pack(a.x, a.y);
    r.u[1] = hi_pack(a.z, a.w);
    r.u[2] = hi_pack(b.x, b.y);
    r.u[3] = hi_pack(b.z, b.w);
    return r.v;
}

__device__ __forceinline__ bf16x8 pack_lo8(float4 a, float4 b) {
    BF8 r;
    r.u[0] = hi_pack(lo_of(a.x), lo_of(a.y));
    r.u[1] = hi_pack(lo_of(a.z), lo_of(a.w));
    r.u[2] = hi_pack(lo_of(b.x), lo_of(b.y));
    r.u[3] = hi_pack(lo_of(b.z), lo_of(b.w));
    return r.v;
}

// ---- pre-split gate_w (64x4096 fp32) into bf16 hi/lo planes in workspace
__global__ __launch_bounds__(256)
void presplit_kernel(const float* __restrict__ gw,
                     unsigned short* __restrict__ whi,
                     unsigned short* __restrict__ wlo) {
    int i = (blockIdx.x * 256 + threadIdx.x) * 4;
    float4 v = *(const float4*)(gw + i);
    ushort4 hi = make_ushort4((unsigned short)(__float_as_uint(v.x) >> 16),
                              (unsigned short)(__float_as_uint(v.y) >> 16),
                              (unsigned short)(__float_as_uint(v.z) >> 16),
                              (unsigned short)(__float_as_uint(v.w) >> 16));
    ushort4 lo = make_ushort4((unsigned short)(__float_as_uint(lo_of(v.x)) >> 16),
                              (unsigned short)(__float_as_uint(lo_of(v.y)) >> 16),
                              (unsigned short)(__float_as_uint(lo_of(v.z)) >> 16),
                              (unsigned short)(__float_as_uint(lo_of(v.w)) >> 16));
    *(ushort4*)(whi + i) = hi;
    *(ushort4*)(wlo + i) = lo;
}

// PS = true: B pre-split in workspace. PS = false: convert B from fp32 inline.
template <bool PS>
__global__ __launch_bounds__(256, 4)
void gating_kernel(const float* __restrict__ x,
                   const float* __restrict__ gw,
                   const unsigned short* __restrict__ whi,
                   const unsigned short* __restrict__ wlo,
                   const float* __restrict__ gb,
                   float* __restrict__ out) {
    __shared__ float lg[BT * LG_S];     // 16 x 65 fp32 logits
    __shared__ float thr9s[BT];
    __shared__ int flags[BT], flist[BT], fcnt;

    const int tid  = threadIdx.x;
    const int ln   = tid & 63;
    const int wv   = __builtin_amdgcn_readfirstlane(tid >> 6);  // 0..3
    const int tok0 = blockIdx.x * BT;
    const int eb   = wv * 16;          // wave's 16 experts
    const int mr   = ln & 15;
    const int q    = ln >> 4;

    // A fragment: lane = token row (mr), 8 contiguous k at q*8
    const float* a_p = x + (size_t)(tok0 + mr) * HID + q * 8;
    // B fragment: lane = expert col (mr), 8 contiguous k at q*8
    const float*          b_p = gw  + (size_t)(eb + mr) * HID + q * 8;
    const unsigned short* h_p = whi + (size_t)(eb + mr) * HID + q * 8;
    const unsigned short* l_p = wlo + (size_t)(eb + mr) * HID + q * 8;

    f32x4 acc = {0.f, 0.f, 0.f, 0.f};

    // double-buffered register pipeline (all indices static under unroll)
    float4 pa[2][2];
    bf16x8 ph[2], pl[2];
    float4 pb[2][2];

    // prologue: chunk 0 -> slot 0
    pa[0][0] = *(const float4*)(a_p + 0);
    pa[0][1] = *(const float4*)(a_p + 4);
    if constexpr (PS) {
        ph[0] = *(const bf16x8*)(h_p + 0);
        pl[0] = *(const bf16x8*)(l_p + 0);
    } else {
        pb[0][0] = *(const float4*)(b_p + 0);
        pb[0][1] = *(const float4*)(b_p + 4);
    }

    // 128 chunks of K=32, 16 per group; raw s_barrier per group bounds drift
    for (int g = 0; g < 8; ++g) {
#pragma unroll
        for (int u = 0; u < 16; ++u) {
            const int slot = u & 1;
            const int ns   = slot ^ 1;
            if (g * 16 + u + 1 < 128) {      // compile-time true except u==15
                const int off = (u + 1) * 32;
                pa[ns][0] = *(const float4*)(a_p + off);
                pa[ns][1] = *(const float4*)(a_p + off + 4);
                if constexpr (PS) {
                    ph[ns] = *(const bf16x8*)(h_p + off);
                    pl[ns] = *(const bf16x8*)(l_p + off);
                } else {
                    pb[ns][0] = *(const float4*)(b_p + off);
                    pb[ns][1] = *(const float4*)(b_p + off + 4);
                }
            }
            bf16x8 ah = pack_hi8(pa[slot][0], pa[slot][1]);
            bf16x8 al = pack_lo8(pa[slot][0], pa[slot][1]);
            bf16x8 bh, bl;
            if constexpr (PS) {
                bh = ph[slot]; bl = pl[slot];
            } else {
                bh = pack_hi8(pb[slot][0], pb[slot][1]);
                bl = pack_lo8(pb[slot][0], pb[slot][1]);
            }
            acc = __builtin_amdgcn_mfma_f32_16x16x32_bf16(ah, bh, acc, 0, 0, 0);
            acc = __builtin_amdgcn_mfma_f32_16x16x32_bf16(ah, bl, acc, 0, 0, 0);
            acc = __builtin_amdgcn_mfma_f32_16x16x32_bf16(al, bh, acc, 0, 0, 0);
            acc = __builtin_amdgcn_mfma_f32_16x16x32_bf16(al, bl, acc, 0, 0, 0);
        }
        a_p += 512; h_p += 512; l_p += 512; b_p += 512;
        __builtin_amdgcn_s_barrier();   // drift bound only; no vmcnt drain
    }

    // ---- epilogue: C/D layout row=(ln>>4)*4+reg (token), col=ln&15 (expert)
    {
        const int e0 = eb + mr;
        const float bb = gb[e0];
#pragma unroll
        for (int i = 0; i < 4; ++i)
            lg[(q * 4 + i) * LG_S + e0] = acc[i] + bb;
    }
    if (tid == 0) fcnt = 0;
    __syncthreads();

    // ---- wave-parallel top-9: token t = wv*4+q, lane mr holds experts 4mr..4mr+3
    const int t = wv * 4 + q;
    float v0 = lg[t * LG_S + mr * 4 + 0];
    float v1 = lg[t * LG_S + mr * 4 + 1];
    float v2 = lg[t * LG_S + mr * 4 + 2];
    float v3 = lg[t * LG_S + mr * 4 + 3];
    float vals9[9];
    int idx9[9];
#pragma unroll
    for (int kk = 0; kk < 9; ++kk) {
        float bv = v0; int bj = 0;
        if (v1 > bv) { bv = v1; bj = 1; }
        if (v2 > bv) { bv = v2; bj = 2; }
        if (v3 > bv) { bv = v3; bj = 3; }
        int be = (mr << 2) | bj;
#pragma unroll
        for (int off = 1; off <= 8; off <<= 1) {
            float ov = __shfl_xor(bv, off);
            int   oe = __shfl_xor(be, off);
            if (ov > bv || (ov == bv && oe < be)) { bv = ov; be = oe; }
        }
        vals9[kk] = bv; idx9[kk] = be;
        if (kk < 8 && (be >> 2) == mr) {
            int j = be & 3;
            v0 = (j == 0) ? -1e30f : v0;
            v1 = (j == 1) ? -1e30f : v1;
            v2 = (j == 2) ? -1e30f : v2;
            v3 = (j == 3) ? -1e30f : v3;
        }
    }
    if (mr == 0) {
        float mg = 1e30f;
#pragma unroll
        for (int kk = 0; kk < 8; kk++) {
            float gp = vals9[kk] - vals9[kk + 1];
            mg = (gp < mg) ? gp : mg;
        }
        int fl = (mg < MARGIN) ? 1 : 0;
        flags[t] = fl;
        thr9s[t] = vals9[8];
        if (!fl) {
            float mx = vals9[0], ex[TOPK], s = 0.f;
#pragma unroll
            for (int k = 0; k < TOPK; k++) { ex[k] = expf(vals9[k] - mx); s += ex[k]; }
            float inv = 1.0f / s;
            int gt = tok0 + t;
#pragma unroll
            for (int k = 0; k < TOPK; k++) {
                out[gt * TOPK + k] = ex[k] * inv;
                out[NT * TOPK + gt * TOPK + k] = (float)idx9[k];
            }
        }
    }
    __syncthreads();

    if (tid == 0) {
        int n = 0;
        for (int tt = 0; tt < BT; tt++) if (flags[tt]) flist[n++] = tt;
        fcnt = n;
    }
    __syncthreads();

    // ---- fp64 fallback: one wave per flagged token, candidate experts only
    for (int i2 = wv; i2 < fcnt; i2 += 4) {
        int tt = flist[i2];
        bool active = lg[tt * LG_S + ln] >= thr9s[tt] - MARGIN;
        double p0 = 0., p1 = 0., p2 = 0., p3 = 0.;
        if (active) {
            const float* xr = x + (size_t)(tok0 + tt) * HID;
            const float* wr = gw + (size_t)ln * HID;
#pragma unroll 4
            for (int k = 0; k < HID; k += 4) {
                float4 a = *(const float4*)(xr + k);
                float4 b = *(const float4*)(wr + k);
                p0 = fma((double)a.x, (double)b.x, p0);
                p1 = fma((double)a.y, (double)b.y, p1);
                p2 = fma((double)a.z, (double)b.z, p2);
                p3 = fma((double)a.w, (double)b.w, p3);
            }
        }
        double base = active ? ((p0 + p1) + (p2 + p3) + (double)gb[ln]) : -1e18;
        double mv[TOPK];
        int mi[TOPK];
#pragma unroll
        for (int k = 0; k < TOPK; k++) {
            double v = base;
            int ii = ln;
#pragma unroll
            for (int off = 32; off >= 1; off >>= 1) {
                double ov = __shfl_xor(v, off);
                int oi = __shfl_xor(ii, off);
                if (ov > v || (ov == v && oi < ii)) { v = ov; ii = oi; }
            }
            mv[k] = v;
            mi[k] = ii;
            if (ln == ii) base = -1e18;
        }
        if (ln == 0) {
            double mx = mv[0];
            float ex[TOPK], s = 0.f;
#pragma unroll
            for (int k = 0; k < TOPK; k++) { ex[k] = expf((float)(mv[k] - mx)); s += ex[k]; }
            float inv = 1.0f / s;
            int gt = tok0 + tt;
#pragma unroll
            for (int k = 0; k < TOPK; k++) {
                out[gt * TOPK + k] = ex[k] * inv;
                out[NT * TOPK + gt * TOPK + k] = (float)mi[k];
            }
        }
    }
}

extern "C" void kernel_launch(void* const* d_in, const int* in_sizes, int n_in,
                              void* d_out, int out_size, void* d_ws, size_t ws_size,
                              hipStream_t stream) {
    const float* x  = (const float*)d_in[0];
    const float* gw = (const float*)d_in[1];
    const float* gb = (const float*)d_in[2];
    float* out = (float*)d_out;

    const size_t ws_need = (size_t)NE * HID * 4;  // hi+lo bf16 planes = 1 MiB
    bool ps = (d_ws != nullptr) && (ws_size >= ws_need);
    if (ps) {
        unsigned short* whi = (unsigned short*)d_ws;
        unsigned short* wlo = whi + (size_t)NE * HID;
        presplit_kernel<<<dim3(NE * HID / 1024), dim3(256), 0, stream>>>(gw, whi, wlo);
        gating_kernel<true><<<dim3(NT / BT), dim3(256), 0, stream>>>(x, gw, whi, wlo, gb, out);
    } else {
        gating_kernel<false><<<dim3(NT / BT), dim3(256), 0, stream>>>(x, gw, nullptr, nullptr, gb, out);
    }
}

// Round 2
// 485.150 us; speedup vs baseline: 1.2773x; 1.2773x over previous
//
#include <hip/hip_runtime.h>
#include <math.h>

// ExpertGating: g = x @ gate_w^T + gate_b (16384x4096 @ 4096x64), top-8 desc
// (tie -> lowest idx), softmax. out: [0,131072) weights, [131072,262144) idx-as-float.
//
// R5: DRAM-burst-oriented restructure.
//   Theory: R3/R4 were latency-bound (~6000 cyc effective) because 16K
//   concurrent row-streams hit HBM at 128-256 B per row-visit -> row-activate
//   thrash. Fix: LDS-staged chunks with 1 KB contiguous burst per row-visit
//   (CK=256 floats, one wave-load instruction = one full row-chunk).
//   - BT=32 tokens/block, 256 thr, grid 512 -> 2 blocks/CU (LDS 74 KB/block).
//   - x staged fp32->bf16 hi/lo planes in LDS, double-buffered, ONE barrier
//     per chunk (16 chunks total vs R3's 128 barriers).
//   - XOR swizzle (ushort idx ^= (row&7)<<3) -> conflict-free ds_read_b128.
//   - B (gate_w) pre-split once to bf16 planes in workspace (L2-resident);
//     per-wave register loads, distance-1 prefetch; wave = 32 tok x 16 exp
//     (2 accumulators) halves B traffic vs R4.
//   - 3 MFMA passes (hh+hl+lh; ll dropped, residual ~2e-6 << MARGIN/2).
//   - Same MARGIN + fp64 fallback; wave-parallel top-9 butterfly epilogue.

#define NT 16384
#define HID 4096
#define NE 64
#define TOPK 8
#define BT 32          // tokens per block
#define CK 256         // K-chunk (floats): 1 KB burst per row-visit
#define NCH (HID / CK) // 16
#define NKS (HID / 32) // 128 global k-steps
#define LG_S 65
#define MARGIN 2.5e-4f

typedef __attribute__((ext_vector_type(8))) short bf16x8;
typedef __attribute__((ext_vector_type(4))) float f32x4;

union BF8 { unsigned int u[4]; bf16x8 v; };

// pack two fp32 -> one dword holding [bf16(b):bf16(a)] (truncation, hi part)
__device__ __forceinline__ unsigned int hi_pack(float a, float b) {
    return __builtin_amdgcn_perm(__float_as_uint(b), __float_as_uint(a), 0x07060302u);
}
__device__ __forceinline__ float lo_of(float f) {
    return f - __uint_as_float(__float_as_uint(f) & 0xFFFF0000u);
}
__device__ __forceinline__ bf16x8 pack_hi8(float4 a, float4 b) {
    BF8 r;
    r.u[0] = hi_pack(a.x, a.y);
    r.u[1] = hi_pack(a.z, a.w);
    r.u[2] = hi_pack(b.x, b.y);
    r.u[3] = hi_pack(b.z, b.w);
    return r.v;
}
__device__ __forceinline__ bf16x8 pack_lo8(float4 a, float4 b) {
    BF8 r;
    r.u[0] = hi_pack(lo_of(a.x), lo_of(a.y));
    r.u[1] = hi_pack(lo_of(a.z), lo_of(a.w));
    r.u[2] = hi_pack(lo_of(b.x), lo_of(b.y));
    r.u[3] = hi_pack(lo_of(b.z), lo_of(b.w));
    return r.v;
}

// ---- pre-split gate_w (64x4096 fp32) into bf16 hi/lo planes in workspace
__global__ __launch_bounds__(256)
void presplit_kernel(const float* __restrict__ gw,
                     unsigned short* __restrict__ whi,
                     unsigned short* __restrict__ wlo) {
    int i = (blockIdx.x * 256 + threadIdx.x) * 4;
    float4 v = *(const float4*)(gw + i);
    ushort4 hi = make_ushort4((unsigned short)(__float_as_uint(v.x) >> 16),
                              (unsigned short)(__float_as_uint(v.y) >> 16),
                              (unsigned short)(__float_as_uint(v.z) >> 16),
                              (unsigned short)(__float_as_uint(v.w) >> 16));
    ushort4 lo = make_ushort4((unsigned short)(__float_as_uint(lo_of(v.x)) >> 16),
                              (unsigned short)(__float_as_uint(lo_of(v.y)) >> 16),
                              (unsigned short)(__float_as_uint(lo_of(v.z)) >> 16),
                              (unsigned short)(__float_as_uint(lo_of(v.w)) >> 16));
    *(ushort4*)(whi + i) = hi;
    *(ushort4*)(wlo + i) = lo;
}

__device__ __forceinline__ void split_store(float4 v, unsigned short* ph,
                                            unsigned short* pl) {
    uint u0 = __float_as_uint(v.x), u1 = __float_as_uint(v.y);
    uint u2 = __float_as_uint(v.z), u3 = __float_as_uint(v.w);
    ushort4 hi = make_ushort4(u0 >> 16, u1 >> 16, u2 >> 16, u3 >> 16);
    ushort4 lo = make_ushort4(__float_as_uint(lo_of(v.x)) >> 16,
                              __float_as_uint(lo_of(v.y)) >> 16,
                              __float_as_uint(lo_of(v.z)) >> 16,
                              __float_as_uint(lo_of(v.w)) >> 16);
    *(ushort4*)ph = hi;
    *(ushort4*)pl = lo;
}

// PS = true: B pre-split in workspace. PS = false: convert B from fp32 inline.
template <bool PS>
__global__ __launch_bounds__(256, 2)
void gating_kernel(const float* __restrict__ x,
                   const float* __restrict__ gw,
                   const unsigned short* __restrict__ whi,
                   const unsigned short* __restrict__ wlo,
                   const float* __restrict__ gb,
                   float* __restrict__ out) {
    __shared__ __align__(16) unsigned short sxh[2][BT * CK];  // 16 KB each
    __shared__ __align__(16) unsigned short sxl[2][BT * CK];
    __shared__ float lg[BT * LG_S];
    __shared__ float thr9s[BT];
    __shared__ int flags[BT], flist[BT], fcnt;

    const int tid  = threadIdx.x;
    const int ln   = tid & 63;
    const int wv   = __builtin_amdgcn_readfirstlane(tid >> 6);  // 0..3
    const int tok0 = blockIdx.x * BT;
    const int eb   = wv * 16;          // wave's 16 experts
    const int mr   = ln & 15;
    const int q    = ln >> 4;

    // stage coords: wave j-th load covers one full 1 KB row-chunk contiguously
    const int srow = wv;               // row = 4*j + srow
    const int scol = ln;               // float4 column within chunk (0..63)

    const float* a_base = x + (size_t)tok0 * HID;

    const unsigned short* hp = whi + (size_t)(eb + mr) * HID + q * 8;
    const unsigned short* lp = wlo + (size_t)(eb + mr) * HID + q * 8;
    const float*          bp = gw  + (size_t)(eb + mr) * HID + q * 8;

    f32x4 acc0 = {0.f, 0.f, 0.f, 0.f};
    f32x4 acc1 = {0.f, 0.f, 0.f, 0.f};

    float4 px[8];
    // ---- prologue: load chunk 0 (each load = 1 KB contiguous per wave)
#pragma unroll
    for (int j = 0; j < 8; j++)
        px[j] = *(const float4*)(a_base + (size_t)(4 * j + srow) * HID + scol * 4);

    bf16x8 pbh, pbl;
    if constexpr (PS) {
        pbh = *(const bf16x8*)hp;
        pbl = *(const bf16x8*)lp;
    } else {
        float4 b0 = *(const float4*)bp;
        float4 b1 = *(const float4*)(bp + 4);
        pbh = pack_hi8(b0, b1);
        pbl = pack_lo8(b0, b1);
    }

    // convert + write chunk 0 -> buf 0 (swizzled: ushort idx ^= (row&7)<<3)
#pragma unroll
    for (int j = 0; j < 8; j++) {
        int r  = 4 * j + srow;
        int ci = r * CK + ((scol * 4) ^ ((r & 7) << 3));
        split_store(px[j], &sxh[0][ci], &sxl[0][ci]);
    }
    __syncthreads();

    for (int ch = 0; ch < NCH; ++ch) {
        const int cb = ch & 1;
        // ---- issue next-chunk loads (in flight across the compute phase)
        if (ch + 1 < NCH) {
            const int k0 = (ch + 1) * CK;
#pragma unroll
            for (int j = 0; j < 8; j++)
                px[j] = *(const float4*)(a_base + (size_t)(4 * j + srow) * HID + k0 + scol * 4);
        }
        // ---- compute 8 k-steps from buf cb
        const unsigned short* bufh = &sxh[cb][0];
        const unsigned short* bufl = &sxl[cb][0];
        const int sw = (mr & 7) << 3;
#pragma unroll
        for (int s = 0; s < 8; ++s) {
            bf16x8 bh = pbh, bl = pbl;
            // distance-1 B prefetch (wrap at end: harmless in-bounds reload)
            const int nk = (ch * 8 + s + 1) & (NKS - 1);
            if constexpr (PS) {
                pbh = *(const bf16x8*)(hp + nk * 32);
                pbl = *(const bf16x8*)(lp + nk * 32);
            } else {
                float4 b0 = *(const float4*)(bp + nk * 32);
                float4 b1 = *(const float4*)(bp + nk * 32 + 4);
                pbh = pack_hi8(b0, b1);
                pbl = pack_lo8(b0, b1);
            }
            const int c0 = (s * 32 + q * 8) ^ sw;
            bf16x8 a0h = *(const bf16x8*)&bufh[mr * CK + c0];
            bf16x8 a0l = *(const bf16x8*)&bufl[mr * CK + c0];
            bf16x8 a1h = *(const bf16x8*)&bufh[(16 + mr) * CK + c0];
            bf16x8 a1l = *(const bf16x8*)&bufl[(16 + mr) * CK + c0];
            acc0 = __builtin_amdgcn_mfma_f32_16x16x32_bf16(a0h, bh, acc0, 0, 0, 0);
            acc0 = __builtin_amdgcn_mfma_f32_16x16x32_bf16(a0h, bl, acc0, 0, 0, 0);
            acc0 = __builtin_amdgcn_mfma_f32_16x16x32_bf16(a0l, bh, acc0, 0, 0, 0);
            acc1 = __builtin_amdgcn_mfma_f32_16x16x32_bf16(a1h, bh, acc1, 0, 0, 0);
            acc1 = __builtin_amdgcn_mfma_f32_16x16x32_bf16(a1h, bl, acc1, 0, 0, 0);
            acc1 = __builtin_amdgcn_mfma_f32_16x16x32_bf16(a1l, bh, acc1, 0, 0, 0);
        }
        // ---- convert + write next chunk -> other buffer
        if (ch + 1 < NCH) {
            const int nb = cb ^ 1;
#pragma unroll
            for (int j = 0; j < 8; j++) {
                int r  = 4 * j + srow;
                int ci = r * CK + ((scol * 4) ^ ((r & 7) << 3));
                split_store(px[j], &sxh[nb][ci], &sxl[nb][ci]);
            }
        }
        __syncthreads();
    }

    // ---- epilogue: C/D layout row=(ln>>4)*4+reg (token), col=ln&15 (expert)
    {
        const int e0 = eb + mr;
        const float bb = gb[e0];
#pragma unroll
        for (int i = 0; i < 4; ++i) {
            lg[(q * 4 + i) * LG_S + e0]      = acc0[i] + bb;
            lg[(16 + q * 4 + i) * LG_S + e0] = acc1[i] + bb;
        }
    }
    if (tid == 0) fcnt = 0;
    __syncthreads();

    // ---- wave-parallel top-9: 16 lanes per token, 2 passes of 16 tokens
#pragma unroll
    for (int p = 0; p < 2; ++p) {
        const int t = p * 16 + wv * 4 + q;
        float v0 = lg[t * LG_S + mr * 4 + 0];
        float v1 = lg[t * LG_S + mr * 4 + 1];
        float v2 = lg[t * LG_S + mr * 4 + 2];
        float v3 = lg[t * LG_S + mr * 4 + 3];
        float vals9[9];
        int idx9[9];
#pragma unroll
        for (int kk = 0; kk < 9; ++kk) {
            float bv = v0; int bj = 0;
            if (v1 > bv) { bv = v1; bj = 1; }
            if (v2 > bv) { bv = v2; bj = 2; }
            if (v3 > bv) { bv = v3; bj = 3; }
            int be = (mr << 2) | bj;
#pragma unroll
            for (int off = 1; off <= 8; off <<= 1) {
                float ov = __shfl_xor(bv, off);
                int   oe = __shfl_xor(be, off);
                if (ov > bv || (ov == bv && oe < be)) { bv = ov; be = oe; }
            }
            vals9[kk] = bv; idx9[kk] = be;
            if (kk < 8 && (be >> 2) == mr) {
                int j = be & 3;
                v0 = (j == 0) ? -1e30f : v0;
                v1 = (j == 1) ? -1e30f : v1;
                v2 = (j == 2) ? -1e30f : v2;
                v3 = (j == 3) ? -1e30f : v3;
            }
        }
        if (mr == 0) {
            float mg = 1e30f;
#pragma unroll
            for (int kk = 0; kk < 8; kk++) {
                float gp = vals9[kk] - vals9[kk + 1];
                mg = (gp < mg) ? gp : mg;
            }
            int fl = (mg < MARGIN) ? 1 : 0;
            flags[t] = fl;
            thr9s[t] = vals9[8];
            if (!fl) {
                float mx = vals9[0], ex[TOPK], s = 0.f;
#pragma unroll
                for (int k = 0; k < TOPK; k++) { ex[k] = expf(vals9[k] - mx); s += ex[k]; }
                float inv = 1.0f / s;
                int gt = tok0 + t;
#pragma unroll
                for (int k = 0; k < TOPK; k++) {
                    out[gt * TOPK + k] = ex[k] * inv;
                    out[NT * TOPK + gt * TOPK + k] = (float)idx9[k];
                }
            }
        }
    }
    __syncthreads();

    if (tid == 0) {
        int n = 0;
        for (int tt = 0; tt < BT; tt++) if (flags[tt]) flist[n++] = tt;
        fcnt = n;
    }
    __syncthreads();

    // ---- fp64 fallback: one wave per flagged token, candidate experts only
    for (int i2 = wv; i2 < fcnt; i2 += 4) {
        int tt = flist[i2];
        bool active = lg[tt * LG_S + ln] >= thr9s[tt] - MARGIN;
        double p0 = 0., p1 = 0., p2 = 0., p3 = 0.;
        if (active) {
            const float* xr = x + (size_t)(tok0 + tt) * HID;
            const float* wr = gw + (size_t)ln * HID;
#pragma unroll 4
            for (int k = 0; k < HID; k += 4) {
                float4 a = *(const float4*)(xr + k);
                float4 b = *(const float4*)(wr + k);
                p0 = fma((double)a.x, (double)b.x, p0);
                p1 = fma((double)a.y, (double)b.y, p1);
                p2 = fma((double)a.z, (double)b.z, p2);
                p3 = fma((double)a.w, (double)b.w, p3);
            }
        }
        double base = active ? ((p0 + p1) + (p2 + p3) + (double)gb[ln]) : -1e18;
        double mv[TOPK];
        int mi[TOPK];
#pragma unroll
        for (int k = 0; k < TOPK; k++) {
            double v = base;
            int ii = ln;
#pragma unroll
            for (int off = 32; off >= 1; off >>= 1) {
                double ov = __shfl_xor(v, off);
                int oi = __shfl_xor(ii, off);
                if (ov > v || (ov == v && oi < ii)) { v = ov; ii = oi; }
            }
            mv[k] = v;
            mi[k] = ii;
            if (ln == ii) base = -1e18;
        }
        if (ln == 0) {
            double mx = mv[0];
            float ex[TOPK], s = 0.f;
#pragma unroll
            for (int k = 0; k < TOPK; k++) { ex[k] = expf((float)(mv[k] - mx)); s += ex[k]; }
            float inv = 1.0f / s;
            int gt = tok0 + tt;
#pragma unroll
            for (int k = 0; k < TOPK; k++) {
                out[gt * TOPK + k] = ex[k] * inv;
                out[NT * TOPK + gt * TOPK + k] = (float)mi[k];
            }
        }
    }
}

extern "C" void kernel_launch(void* const* d_in, const int* in_sizes, int n_in,
                              void* d_out, int out_size, void* d_ws, size_t ws_size,
                              hipStream_t stream) {
    const float* x  = (const float*)d_in[0];
    const float* gw = (const float*)d_in[1];
    const float* gb = (const float*)d_in[2];
    float* out = (float*)d_out;

    const size_t ws_need = (size_t)NE * HID * 4;  // hi+lo bf16 planes = 1 MiB
    bool ps = (d_ws != nullptr) && (ws_size >= ws_need);
    if (ps) {
        unsigned short* whi = (unsigned short*)d_ws;
        unsigned short* wlo = whi + (size_t)NE * HID;
        presplit_kernel<<<dim3(NE * HID / 1024), dim3(256), 0, stream>>>(gw, whi, wlo);
        gating_kernel<true><<<dim3(NT / BT), dim3(256), 0, stream>>>(x, gw, whi, wlo, gb, out);
    } else {
        gating_kernel<false><<<dim3(NT / BT), dim3(256), 0, stream>>>(x, gw, nullptr, nullptr, gb, out);
    }
}